// Round 12
// baseline (2546.920 us; speedup 1.0000x reference)
//
#include <hip/hip_runtime.h>
#include <stdint.h>

#define SEQ 8192
#define B   40
#define EMBD 64
#define HID 40
#define VOCAB 201
#define LOG2E 1.4426950408889634f

typedef _Float16 v2h __attribute__((ext_vector_type(2)));
typedef float    v4f __attribute__((ext_vector_type(4)));

__device__ __forceinline__ float fexp2(float x) { float r; asm("v_exp_f32 %0, %1" : "=v"(r) : "v"(x)); return r; }
__device__ __forceinline__ float frcp (float x) { float r; asm("v_rcp_f32 %0, %1" : "=v"(r) : "v"(x)); return r; }
__device__ __forceinline__ float sigm (float x) { return frcp(1.f + fexp2(-LOG2E * x)); }
__device__ __forceinline__ float tanh_(float x) { return fmaf(2.f, frcp(1.f + fexp2(-2.f * LOG2E * x)), -1.f); }
__device__ __forceinline__ v2h rdpair(v2h v, int k) {
    int r = __builtin_amdgcn_readlane(__builtin_bit_cast(int, v), k);
    return __builtin_bit_cast(v2h, r);
}
__device__ __forceinline__ v2h pkrtz(float lo, float hi) {
    return __builtin_bit_cast(v2h, __builtin_amdgcn_cvt_pkrtz(lo, hi));
}
template <int CTRL>
__device__ __forceinline__ float dppq(float v) {
    return __builtin_bit_cast(float,
        __builtin_amdgcn_update_dpp(0, __builtin_bit_cast(int, v), CTRL, 0xF, 0xF, true));
}

// ---------------- kernel A: table4[v][e] = (i,f,g,o) gate x-parts+bias (fp32) ----------------
__global__ void setup_kernel(const float* __restrict__ emb, const float* __restrict__ Wih,
                             const float* __restrict__ bih, const float* __restrict__ bhh,
                             float4* __restrict__ table4) {
    const int v = blockIdx.x;          // 0..200
    const int e = threadIdx.x;         // 0..63, active < 40
    if (e >= HID) return;
    const float* er = emb + v * EMBD;
    float acc[4];
#pragma unroll
    for (int g = 0; g < 4; ++g) {
        const int j = g * HID + e;
        const float* wr = Wih + j * EMBD;
        float a = bih[j] + bhh[j];
#pragma unroll 8
        for (int k = 0; k < EMBD; ++k) a = fmaf(er[k], wr[k], a);
        acc[g] = a;
    }
    table4[v * HID + e] = make_float4(acc[0], acc[1], acc[2], acc[3]);
}

// ---------------- kernel B: encoder — vmcnt(3) pipeline + 4-way-split accumulator chains ----------------
__global__ __attribute__((amdgpu_flat_work_group_size(64, 64), amdgpu_waves_per_eu(1, 1)))
void enc_kernel(const int* __restrict__ src,
                const float* __restrict__ Whh,
                const float4* __restrict__ tbl,
                float* __restrict__ est) {
    const int b    = blockIdx.x;
    const int lane = threadIdx.x;
    const int e    = (lane < HID) ? lane : 0;   // clamp idle lanes

    __shared__ int ssrc[SEQ];
    for (int t = lane; t < SEQ; t += 64) ssrc[t] = src[t * B + b];

    // weights as f16 pairs -- 80 VGPRs
    v2h wi[20], wf[20], wg[20], wo[20];
#pragma unroll
    for (int r = 0; r < 10; ++r) {
        float4 ai = *reinterpret_cast<const float4*>(&Whh[(0 * HID + e) * HID + 4 * r]);
        float4 af = *reinterpret_cast<const float4*>(&Whh[(1 * HID + e) * HID + 4 * r]);
        float4 ag = *reinterpret_cast<const float4*>(&Whh[(2 * HID + e) * HID + 4 * r]);
        float4 ao = *reinterpret_cast<const float4*>(&Whh[(3 * HID + e) * HID + 4 * r]);
        wi[2*r]   = (v2h){(_Float16)ai.x, (_Float16)ai.y};
        wi[2*r+1] = (v2h){(_Float16)ai.z, (_Float16)ai.w};
        wf[2*r]   = (v2h){(_Float16)af.x, (_Float16)af.y};
        wf[2*r+1] = (v2h){(_Float16)af.z, (_Float16)af.w};
        wg[2*r]   = (v2h){(_Float16)ag.x, (_Float16)ag.y};
        wg[2*r+1] = (v2h){(_Float16)ag.z, (_Float16)ag.w};
        wo[2*r]   = (v2h){(_Float16)ao.x, (_Float16)ao.y};
        wo[2*r+1] = (v2h){(_Float16)ao.z, (_Float16)ao.w};
    }

    __syncthreads();   // ssrc staged

    asm volatile("s_waitcnt vmcnt(0)" ::: "memory");

    const uint64_t base = (uint64_t)(const void*)tbl;
    v4f tq[4];
    int idxw[4];   // idx for step t+4 (slot t&3)
#pragma unroll
    for (int p = 0; p < 4; ++p) {
        uint64_t a = base + ((uint64_t)(uint32_t)(ssrc[p] * HID + e) << 4);
        asm volatile("global_load_dwordx4 %0, %1, off" : "=v"(tq[p]) : "v"(a));
        idxw[p] = ssrc[p + 4];
    }

    float c = 0.f, h = 0.f;
    v2h hpk = (v2h){(_Float16)0.f, (_Float16)0.f};

#pragma unroll 4
    for (int t = 0; t < SEQ; ++t) {
        const int s = t & 3;

        asm volatile("s_waitcnt vmcnt(3)");
        __builtin_amdgcn_sched_barrier(0);
        v4f q = tq[s];

        // 4-way-split accumulator chains per gate (5-deep each)
        float AI0 = q.x, AI1 = 0.f, AI2 = 0.f, AI3 = 0.f;
        float AF0 = q.y, AF1 = 0.f, AF2 = 0.f, AF3 = 0.f;
        float AG0 = q.z, AG1 = 0.f, AG2 = 0.f, AG3 = 0.f;
        float AO0 = q.w, AO1 = 0.f, AO2 = 0.f, AO3 = 0.f;
#pragma unroll
        for (int m = 0; m < 20; m += 4) {
            v2h h0 = rdpair(hpk, 2 * m);
            v2h h1 = rdpair(hpk, 2 * m + 2);
            v2h h2 = rdpair(hpk, 2 * m + 4);
            v2h h3 = rdpair(hpk, 2 * m + 6);
            AI0 = __builtin_amdgcn_fdot2(wi[m],   h0, AI0, false);
            AF0 = __builtin_amdgcn_fdot2(wf[m],   h0, AF0, false);
            AG0 = __builtin_amdgcn_fdot2(wg[m],   h0, AG0, false);
            AO0 = __builtin_amdgcn_fdot2(wo[m],   h0, AO0, false);
            AI1 = __builtin_amdgcn_fdot2(wi[m+1], h1, AI1, false);
            AF1 = __builtin_amdgcn_fdot2(wf[m+1], h1, AF1, false);
            AG1 = __builtin_amdgcn_fdot2(wg[m+1], h1, AG1, false);
            AO1 = __builtin_amdgcn_fdot2(wo[m+1], h1, AO1, false);
            AI2 = __builtin_amdgcn_fdot2(wi[m+2], h2, AI2, false);
            AF2 = __builtin_amdgcn_fdot2(wf[m+2], h2, AF2, false);
            AG2 = __builtin_amdgcn_fdot2(wg[m+2], h2, AG2, false);
            AO2 = __builtin_amdgcn_fdot2(wo[m+2], h2, AO2, false);
            AI3 = __builtin_amdgcn_fdot2(wi[m+3], h3, AI3, false);
            AF3 = __builtin_amdgcn_fdot2(wf[m+3], h3, AF3, false);
            AG3 = __builtin_amdgcn_fdot2(wg[m+3], h3, AG3, false);
            AO3 = __builtin_amdgcn_fdot2(wo[m+3], h3, AO3, false);
        }
        float AI = (AI0 + AI1) + (AI2 + AI3);
        float AF = (AF0 + AF1) + (AF2 + AF3);
        float AG = (AG0 + AG1) + (AG2 + AG3);
        float AO = (AO0 + AO1) + (AO2 + AO3);

        float si = sigm(AI), sf = sigm(AF), tg = tanh_(AG), so = sigm(AO);
        c = fmaf(sf, c, si * tg);
        h = so * tanh_(c);

        // repack h into f16 pairs via DPP quad_perm
        float hA = dppq<0xA0>(h);   // [0,0,2,2]
        float hB = dppq<0xF5>(h);   // [1,1,3,3]
        hpk = pkrtz(hA, hB);

        // issue load for step t+4 into the slot just consumed
        uint64_t a = base + ((uint64_t)(uint32_t)(idxw[s] * HID + e) << 4);
        asm volatile("global_load_dwordx4 %0, %1, off" : "=v"(tq[s]) : "v"(a));
        idxw[s] = ssrc[(t + 8) & (SEQ - 1)];
    }

    if (lane < HID) {
        est[b * 80 + lane]       = h;
        est[b * 80 + HID + lane] = c;
    }
}

// ---------------- kernel C: decoder, 40 steps, 1 chain per block (3 waves, fp32) ----------------
__global__ __launch_bounds__(192, 1) void dec_kernel(const float* __restrict__ dinp,
                                                     const float* __restrict__ Wih,
                                                     const float* __restrict__ Whh,
                                                     const float* __restrict__ bih,
                                                     const float* __restrict__ bhh,
                                                     const float* __restrict__ est,
                                                     float* __restrict__ out) {
    const int b    = blockIdx.x;
    const int tid  = threadIdx.x;
    const int lane = tid & 63;
    const int w    = tid >> 6;
    const int tt   = lane >> 4;
    const int q    = lane & 15;
    const int e    = 16 * w + q;
    const bool valid = (e < HID);
    const bool own   = valid && (tt == 0);
    const int j    = tt * HID + (valid ? e : 0);

    __shared__ __align__(16) float hbuf[2][48];

    float4 wi4[10], wh4[10];
#pragma unroll
    for (int r = 0; r < 10; ++r) {
        float4 ti = *reinterpret_cast<const float4*>(&Wih[j * HID + 4 * r]);
        float4 th = *reinterpret_cast<const float4*>(&Whh[j * HID + 4 * r]);
        if (!valid) { ti = make_float4(0,0,0,0); th = make_float4(0,0,0,0); }
        wi4[r] = ti; wh4[r] = th;
    }
    const float bj = valid ? (bih[j] + bhh[j]) : 0.f;

    const float mcoef = (tt == 2) ? (-2.f * LOG2E) : (-LOG2E);
    const float vsc   = (tt == 2) ? 2.f : 1.f;
    const float voff  = (tt == 2) ? -1.f : 0.f;

    float4 xr4[10], hr4[10];
#pragma unroll
    for (int r = 0; r < 10; ++r) {
        xr4[r] = *reinterpret_cast<const float4*>(&dinp[b * HID + 4 * r]);
        hr4[r] = *reinterpret_cast<const float4*>(&est[b * 80 + 4 * r]);
    }
    float c = valid ? est[b * 80 + HID + e] : 0.f;

    for (int t = 0; t < B; ++t) {
        float a0 = bj, a1 = 0.f, a2 = 0.f, a3 = 0.f;
#pragma unroll
        for (int r = 0; r < 10; ++r) {
            a0 = fmaf(wi4[r].x, xr4[r].x, a0);
            a1 = fmaf(wi4[r].y, xr4[r].y, a1);
            a2 = fmaf(wi4[r].z, xr4[r].z, a2);
            a3 = fmaf(wi4[r].w, xr4[r].w, a3);
            a0 = fmaf(wh4[r].x, hr4[r].x, a0);
            a1 = fmaf(wh4[r].y, hr4[r].y, a1);
            a2 = fmaf(wh4[r].z, hr4[r].z, a2);
            a3 = fmaf(wh4[r].w, hr4[r].w, a3);
        }
        float xg = (a0 + a1) + (a2 + a3);

        float E   = fexp2(mcoef * xg);
        float v   = frcp(1.f + E);
        float act = fmaf(vsc, v, voff);

        float ig = __shfl(act, q);
        float fg = __shfl(act, q + 16);
        float gg = __shfl(act, q + 32);
        float og = __shfl(act, q + 48);

        c = fmaf(fg, c, ig * gg);
        float Ec = fexp2(-2.f * LOG2E * c);
        float th = fmaf(2.f, frcp(1.f + Ec), -1.f);
        float h  = og * th;

        if (own) out[(t * B + b) * HID + e] = h;

        if (own) hbuf[t & 1][e] = h;
        __syncthreads();
#pragma unroll
        for (int r = 0; r < 10; ++r) {
            hr4[r] = *reinterpret_cast<const float4*>(&hbuf[t & 1][4 * r]);
            xr4[r] = hr4[r];   // next input is current output
        }
    }
}

extern "C" void kernel_launch(void* const* d_in, const int* in_sizes, int n_in,
                              void* d_out, int out_size, void* d_ws, size_t ws_size,
                              hipStream_t stream) {
    const int*   src  = (const int*)  d_in[0];
    const float* dinp = (const float*)d_in[1];
    const float* emb  = (const float*)d_in[2];
    const float* eWih = (const float*)d_in[3];
    const float* eWhh = (const float*)d_in[4];
    const float* ebih = (const float*)d_in[5];
    const float* ebhh = (const float*)d_in[6];
    const float* dWih = (const float*)d_in[7];
    const float* dWhh = (const float*)d_in[8];
    const float* dbih = (const float*)d_in[9];
    const float* dbhh = (const float*)d_in[10];
    float* out = (float*)d_out;

    float4* table4 = (float4*)d_ws;                       // 201*40 float4
    float*  est    = (float*)(table4 + VOCAB * HID);      // 40*80 floats

    hipLaunchKernelGGL(setup_kernel, dim3(VOCAB), dim3(64), 0, stream, emb, eWih, ebih, ebhh, table4);
    hipLaunchKernelGGL(enc_kernel,   dim3(B),     dim3(64), 0, stream, src, eWhh, table4, est);
    hipLaunchKernelGGL(dec_kernel,   dim3(B),     dim3(192), 0, stream, dinp, dWih, dWhh, dbih, dbhh, est, out);
}

// Round 14
// 1853.036 us; speedup vs baseline: 1.3745x; 1.3745x over previous
//
#include <hip/hip_runtime.h>
#include <stdint.h>

#define SEQ 8192
#define B   40
#define EMBD 64
#define HID 40
#define VOCAB 201
#define LOG2E 1.4426950408889634f

typedef _Float16 v2h __attribute__((ext_vector_type(2)));

__device__ __forceinline__ float fexp2(float x) { float r; asm("v_exp_f32 %0, %1" : "=v"(r) : "v"(x)); return r; }
__device__ __forceinline__ float frcp (float x) { float r; asm("v_rcp_f32 %0, %1" : "=v"(r) : "v"(x)); return r; }
__device__ __forceinline__ float tanh_(float x) { return fmaf(2.f, frcp(1.f + fexp2(-2.f * LOG2E * x)), -1.f); }
__device__ __forceinline__ v2h rdpair(v2h v, int k) {
    int r = __builtin_amdgcn_readlane(__builtin_bit_cast(int, v), k);
    return __builtin_bit_cast(v2h, r);
}
__device__ __forceinline__ v2h pkrtz(float lo, float hi) {
    return __builtin_bit_cast(v2h, __builtin_amdgcn_cvt_pkrtz(lo, hi));
}
template <int CTRL>
__device__ __forceinline__ float dppq(float v) {
    return __builtin_bit_cast(float,
        __builtin_amdgcn_update_dpp(0, __builtin_bit_cast(int, v), CTRL, 0xF, 0xF, true));
}

// ---------------- kernel A: gate-major NON-scaled table ----------------
// tabg[(g*VOCAB+v)*HID+e] = bih+bhh + Wih·emb[v]   (R9-proven numerics)
__global__ void setup_kernel(const float* __restrict__ emb, const float* __restrict__ Wih,
                             const float* __restrict__ bih, const float* __restrict__ bhh,
                             float* __restrict__ tabg) {
    const int v = blockIdx.x;          // 0..200
    const int e = threadIdx.x;         // 0..63, active < 40
    if (e >= HID) return;
    const float* er = emb + v * EMBD;
#pragma unroll
    for (int g = 0; g < 4; ++g) {
        const int j = g * HID + e;
        const float* wr = Wih + j * EMBD;
        float a = bih[j] + bhh[j];
#pragma unroll 8
        for (int k = 0; k < EMBD; ++k) a = fmaf(er[k], wr[k], a);
        tabg[(g * VOCAB + v) * HID + e] = a;
    }
}

// ---------------- kernel B: encoder — 4 waves/chain gate-split, R9 numerics ----------------
__global__ __attribute__((amdgpu_flat_work_group_size(256, 256), amdgpu_waves_per_eu(1, 1)))
void enc_kernel(const int* __restrict__ src,
                const float* __restrict__ Whh,
                const float* __restrict__ tabg,
                float* __restrict__ est) {
    const int b    = blockIdx.x;
    const int tid  = threadIdx.x;
    const int lane = tid & 63;
    const int wg   = tid >> 6;                  // gate 0..3 (i,f,g,o)
    const int e    = (lane < HID) ? lane : 0;   // clamp idle lanes

    __shared__ int ssrc[SEQ];
    __shared__ __align__(16) float act[2][48][4];   // [parity][element][gate]

    for (int t = tid; t < SEQ; t += 256) ssrc[t] = src[t * B + b];

    // this wave's gate row for element e, NON-scaled f16 pairs (20 VGPRs)
    v2h w[20];
    {
        const float* row = &Whh[(wg * HID + e) * HID];
#pragma unroll
        for (int r = 0; r < 10; ++r) {
            float4 a4 = *reinterpret_cast<const float4*>(&row[4 * r]);
            w[2*r]   = (v2h){(_Float16)a4.x, (_Float16)a4.y};
            w[2*r+1] = (v2h){(_Float16)a4.z, (_Float16)a4.w};
        }
    }
    // wave-uniform activation constants: sigmoid (i,f,o) or tanh (g)
    const float mcoef = (wg == 2) ? (-2.f * LOG2E) : (-LOG2E);
    const float vsc   = (wg == 2) ? 2.f : 1.f;
    const float voff  = (wg == 2) ? -1.f : 0.f;

    __syncthreads();   // ssrc staged

    asm volatile("s_waitcnt vmcnt(0)" ::: "memory");

    // per-lane x base: tabg + (wg*VOCAB*HID + e)*4 ; step addr = base + idx*HID*4
    const uint64_t base = (uint64_t)(const void*)tabg
                        + ((uint64_t)(uint32_t)(wg * VOCAB * HID + e) << 2);
    float tq[4];
    int idxw[4];
#pragma unroll
    for (int p = 0; p < 4; ++p) {
        uint64_t a = base + (uint64_t)((uint32_t)(ssrc[p] * HID) << 2);
        asm volatile("global_load_dword %0, %1, off" : "=v"(tq[p]) : "v"(a));
        idxw[p] = ssrc[p + 4];
    }

    float c = 0.f, h = 0.f;
    v2h hpk = (v2h){(_Float16)0.f, (_Float16)0.f};

#pragma unroll 4
    for (int t = 0; t < SEQ; ++t) {
        const int s = t & 3;
        const int p = t & 1;

        asm volatile("s_waitcnt vmcnt(3)");
        __builtin_amdgcn_sched_barrier(0);
        float A = tq[s];     // fp32 x-part seed (non-scaled)

        // this gate's dot over h (20 fdot2, readlane broadcast) — R9 chain
#pragma unroll
        for (int m = 0; m < 20; ++m) {
            v2h hm = rdpair(hpk, 2 * m);
            A = __builtin_amdgcn_fdot2(w[m], hm, A, false);
        }
        // activation: act = vsc * rcp(1+exp2(mcoef*A)) + voff
        float a_ = fmaf(vsc, frcp(1.f + fexp2(mcoef * A)), voff);

        act[p][e][wg] = a_;
        __syncthreads();
        float4 g4 = *reinterpret_cast<const float4*>(&act[p][e][0]);  // si,sf,tg,so

        c = fmaf(g4.y, c, g4.x * g4.z);
        h = g4.w * tanh_(c);

        // repack h into f16 pairs via DPP quad_perm (every wave, redundant)
        float hA = dppq<0xA0>(h);
        float hB = dppq<0xF5>(h);
        hpk = pkrtz(hA, hB);

        // issue x-load for step t+4
        uint64_t a = base + (uint64_t)((uint32_t)(idxw[s] * HID) << 2);
        asm volatile("global_load_dword %0, %1, off" : "=v"(tq[s]) : "v"(a));
        idxw[s] = ssrc[(t + 8) & (SEQ - 1)];
    }

    if (tid < HID) {
        est[b * 80 + tid]       = h;
        est[b * 80 + HID + tid] = c;
    }
}

// ---------------- kernel C: decoder, 40 steps, 1 chain per block (3 waves, fp32) ----------------
__global__ __launch_bounds__(192, 1) void dec_kernel(const float* __restrict__ dinp,
                                                     const float* __restrict__ Wih,
                                                     const float* __restrict__ Whh,
                                                     const float* __restrict__ bih,
                                                     const float* __restrict__ bhh,
                                                     const float* __restrict__ est,
                                                     float* __restrict__ out) {
    const int b    = blockIdx.x;
    const int tid  = threadIdx.x;
    const int lane = tid & 63;
    const int w    = tid >> 6;
    const int tt   = lane >> 4;
    const int q    = lane & 15;
    const int e    = 16 * w + q;
    const bool valid = (e < HID);
    const bool own   = valid && (tt == 0);
    const int j    = tt * HID + (valid ? e : 0);

    __shared__ __align__(16) float hbuf[2][48];

    float4 wi4[10], wh4[10];
#pragma unroll
    for (int r = 0; r < 10; ++r) {
        float4 ti = *reinterpret_cast<const float4*>(&Wih[j * HID + 4 * r]);
        float4 th = *reinterpret_cast<const float4*>(&Whh[j * HID + 4 * r]);
        if (!valid) { ti = make_float4(0,0,0,0); th = make_float4(0,0,0,0); }
        wi4[r] = ti; wh4[r] = th;
    }
    const float bj = valid ? (bih[j] + bhh[j]) : 0.f;

    const float mcoef = (tt == 2) ? (-2.f * LOG2E) : (-LOG2E);
    const float vsc   = (tt == 2) ? 2.f : 1.f;
    const float voff  = (tt == 2) ? -1.f : 0.f;

    float4 xr4[10], hr4[10];
#pragma unroll
    for (int r = 0; r < 10; ++r) {
        xr4[r] = *reinterpret_cast<const float4*>(&dinp[b * HID + 4 * r]);
        hr4[r] = *reinterpret_cast<const float4*>(&est[b * 80 + 4 * r]);
    }
    float c = valid ? est[b * 80 + HID + e] : 0.f;

    for (int t = 0; t < B; ++t) {
        float a0 = bj, a1 = 0.f, a2 = 0.f, a3 = 0.f;
#pragma unroll
        for (int r = 0; r < 10; ++r) {
            a0 = fmaf(wi4[r].x, xr4[r].x, a0);
            a1 = fmaf(wi4[r].y, xr4[r].y, a1);
            a2 = fmaf(wi4[r].z, xr4[r].z, a2);
            a3 = fmaf(wi4[r].w, xr4[r].w, a3);
            a0 = fmaf(wh4[r].x, hr4[r].x, a0);
            a1 = fmaf(wh4[r].y, hr4[r].y, a1);
            a2 = fmaf(wh4[r].z, hr4[r].z, a2);
            a3 = fmaf(wh4[r].w, hr4[r].w, a3);
        }
        float xg = (a0 + a1) + (a2 + a3);

        float E   = fexp2(mcoef * xg);
        float v   = frcp(1.f + E);
        float act = fmaf(vsc, v, voff);

        float ig = __shfl(act, q);
        float fg = __shfl(act, q + 16);
        float gg = __shfl(act, q + 32);
        float og = __shfl(act, q + 48);

        c = fmaf(fg, c, ig * gg);
        float Ec = fexp2(-2.f * LOG2E * c);
        float th = fmaf(2.f, frcp(1.f + Ec), -1.f);
        float h  = og * th;

        if (own) out[(t * B + b) * HID + e] = h;

        if (own) hbuf[t & 1][e] = h;
        __syncthreads();
#pragma unroll
        for (int r = 0; r < 10; ++r) {
            hr4[r] = *reinterpret_cast<const float4*>(&hbuf[t & 1][4 * r]);
            xr4[r] = hr4[r];   // next input is current output
        }
    }
}

extern "C" void kernel_launch(void* const* d_in, const int* in_sizes, int n_in,
                              void* d_out, int out_size, void* d_ws, size_t ws_size,
                              hipStream_t stream) {
    const int*   src  = (const int*)  d_in[0];
    const float* dinp = (const float*)d_in[1];
    const float* emb  = (const float*)d_in[2];
    const float* eWih = (const float*)d_in[3];
    const float* eWhh = (const float*)d_in[4];
    const float* ebih = (const float*)d_in[5];
    const float* ebhh = (const float*)d_in[6];
    const float* dWih = (const float*)d_in[7];
    const float* dWhh = (const float*)d_in[8];
    const float* dbih = (const float*)d_in[9];
    const float* dbhh = (const float*)d_in[10];
    float* out = (float*)d_out;

    float* tabg = (float*)d_ws;                           // 4*201*40 floats (gate-major)
    float* est  = tabg + 4 * VOCAB * HID;                 // 40*80 floats

    hipLaunchKernelGGL(setup_kernel, dim3(VOCAB), dim3(64),  0, stream, emb, eWih, ebih, ebhh, tabg);
    hipLaunchKernelGGL(enc_kernel,   dim3(B),     dim3(256), 0, stream, src, eWhh, tabg, est);
    hipLaunchKernelGGL(dec_kernel,   dim3(B),     dim3(192), 0, stream, dinp, dWih, dWhh, dbih, dbhh, est, out);
}